// Round 1
// baseline (106.045 us; speedup 1.0000x reference)
//
#include <hip/hip_runtime.h>
#include <hip/hip_bf16.h>

// Elementwise rsqrt(x) over N fp32 elements. Memory-bound streaming kernel:
// float4 vectorized, grid-stride, grid capped at 2048 blocks (256 CU x 8).

__global__ void rsqrt_kernel_v4(const float4* __restrict__ x, float4* __restrict__ out,
                                long long n4) {
    long long i = (long long)blockIdx.x * blockDim.x + threadIdx.x;
    long long stride = (long long)gridDim.x * blockDim.x;
    for (; i < n4; i += stride) {
        float4 v = x[i];
        float4 r;
        r.x = rsqrtf(v.x);
        r.y = rsqrtf(v.y);
        r.z = rsqrtf(v.z);
        r.w = rsqrtf(v.w);
        out[i] = r;
    }
}

// Scalar tail kernel (not needed for N % 4 == 0, but kept for generality).
__global__ void rsqrt_kernel_tail(const float* __restrict__ x, float* __restrict__ out,
                                  long long start, long long n) {
    long long i = start + (long long)blockIdx.x * blockDim.x + threadIdx.x;
    if (i < n) out[i] = rsqrtf(x[i]);
}

extern "C" void kernel_launch(void* const* d_in, const int* in_sizes, int n_in,
                              void* d_out, int out_size, void* d_ws, size_t ws_size,
                              hipStream_t stream) {
    const float* x = (const float*)d_in[0];
    float* out = (float*)d_out;
    long long n = (long long)in_sizes[0];

    long long n4 = n / 4;
    const int block = 256;
    int grid = (int)((n4 + block - 1) / block);
    if (grid > 2048) grid = 2048;
    if (grid > 0) {
        rsqrt_kernel_v4<<<grid, block, 0, stream>>>((const float4*)x, (float4*)out, n4);
    }
    long long tail_start = n4 * 4;
    long long tail = n - tail_start;
    if (tail > 0) {
        int tgrid = (int)((tail + block - 1) / block);
        rsqrt_kernel_tail<<<tgrid, block, 0, stream>>>(x, out, tail_start, n);
    }
}

// Round 2
// 100.038 us; speedup vs baseline: 1.0600x; 1.0600x over previous
//
#include <hip/hip_runtime.h>
#include <hip/hip_bf16.h>

// Elementwise rsqrt(x) over N fp32. Streaming, memory-bound.
// v2: nontemporal loads/stores (no cache allocation for 512 MB of
// zero-reuse traffic) + 2-way unrolled grid-stride loop for MLP.

typedef float f32x4 __attribute__((ext_vector_type(4)));

__global__ void rsqrt_kernel_v4(const f32x4* __restrict__ x, f32x4* __restrict__ out,
                                long long n4) {
    long long stride = (long long)gridDim.x * blockDim.x;
    long long i = (long long)blockIdx.x * blockDim.x + threadIdx.x;

    // 2-way unrolled main loop: two independent loads in flight per thread.
    for (; i + stride < n4; i += 2 * stride) {
        f32x4 a = __builtin_nontemporal_load(&x[i]);
        f32x4 b = __builtin_nontemporal_load(&x[i + stride]);
        f32x4 ra, rb;
        ra.x = rsqrtf(a.x); ra.y = rsqrtf(a.y); ra.z = rsqrtf(a.z); ra.w = rsqrtf(a.w);
        rb.x = rsqrtf(b.x); rb.y = rsqrtf(b.y); rb.z = rsqrtf(b.z); rb.w = rsqrtf(b.w);
        __builtin_nontemporal_store(ra, &out[i]);
        __builtin_nontemporal_store(rb, &out[i + stride]);
    }
    if (i < n4) {
        f32x4 a = __builtin_nontemporal_load(&x[i]);
        f32x4 ra;
        ra.x = rsqrtf(a.x); ra.y = rsqrtf(a.y); ra.z = rsqrtf(a.z); ra.w = rsqrtf(a.w);
        __builtin_nontemporal_store(ra, &out[i]);
    }
}

// Scalar tail (unused for N % 4 == 0; kept for generality).
__global__ void rsqrt_kernel_tail(const float* __restrict__ x, float* __restrict__ out,
                                  long long start, long long n) {
    long long i = start + (long long)blockIdx.x * blockDim.x + threadIdx.x;
    if (i < n) out[i] = rsqrtf(x[i]);
}

extern "C" void kernel_launch(void* const* d_in, const int* in_sizes, int n_in,
                              void* d_out, int out_size, void* d_ws, size_t ws_size,
                              hipStream_t stream) {
    const float* x = (const float*)d_in[0];
    float* out = (float*)d_out;
    long long n = (long long)in_sizes[0];

    long long n4 = n / 4;
    const int block = 256;
    int grid = (int)((n4 + block - 1) / block);
    if (grid > 2048) grid = 2048;
    if (grid > 0) {
        rsqrt_kernel_v4<<<grid, block, 0, stream>>>((const f32x4*)x, (f32x4*)out, n4);
    }
    long long tail_start = n4 * 4;
    long long tail = n - tail_start;
    if (tail > 0) {
        int tgrid = (int)((tail + block - 1) / block);
        rsqrt_kernel_tail<<<tgrid, block, 0, stream>>>(x, out, tail_start, n);
    }
}

// Round 3
// 87.991 us; speedup vs baseline: 1.2052x; 1.1369x over previous
//
#include <hip/hip_runtime.h>
#include <hip/hip_bf16.h>

// Elementwise rsqrt(x) over N fp32. Streaming, memory-bound.
// v3: exact static partition for N = 64M — grid 8192 x block 256 x 8 float4
// per thread, fully unrolled, 32-bit indexing, no bounds checks, nt hints.
// Generic grid-stride fallback for any other N.

typedef float f32x4 __attribute__((ext_vector_type(4)));

// Static kernel: n4 == GRID*BLOCK*PER_THREAD exactly. Block covers a
// contiguous 256*8 float4 = 32 KB chunk; each wave load is a contiguous 1 KB.
__global__ void __launch_bounds__(256) rsqrt_kernel_static(
        const f32x4* __restrict__ x, f32x4* __restrict__ out) {
    constexpr int PER_THREAD = 8;
    const int base = blockIdx.x * (256 * PER_THREAD) + threadIdx.x;

    f32x4 v[PER_THREAD];
#pragma unroll
    for (int k = 0; k < PER_THREAD; ++k)
        v[k] = __builtin_nontemporal_load(&x[base + k * 256]);
#pragma unroll
    for (int k = 0; k < PER_THREAD; ++k) {
        f32x4 r;
        r.x = rsqrtf(v[k].x); r.y = rsqrtf(v[k].y);
        r.z = rsqrtf(v[k].z); r.w = rsqrtf(v[k].w);
        __builtin_nontemporal_store(r, &out[base + k * 256]);
    }
}

// Generic fallback: 2-way unrolled grid-stride.
__global__ void rsqrt_kernel_v4(const f32x4* __restrict__ x, f32x4* __restrict__ out,
                                long long n4) {
    long long stride = (long long)gridDim.x * blockDim.x;
    long long i = (long long)blockIdx.x * blockDim.x + threadIdx.x;
    for (; i + stride < n4; i += 2 * stride) {
        f32x4 a = __builtin_nontemporal_load(&x[i]);
        f32x4 b = __builtin_nontemporal_load(&x[i + stride]);
        f32x4 ra, rb;
        ra.x = rsqrtf(a.x); ra.y = rsqrtf(a.y); ra.z = rsqrtf(a.z); ra.w = rsqrtf(a.w);
        rb.x = rsqrtf(b.x); rb.y = rsqrtf(b.y); rb.z = rsqrtf(b.z); rb.w = rsqrtf(b.w);
        __builtin_nontemporal_store(ra, &out[i]);
        __builtin_nontemporal_store(rb, &out[i + stride]);
    }
    if (i < n4) {
        f32x4 a = __builtin_nontemporal_load(&x[i]);
        f32x4 ra;
        ra.x = rsqrtf(a.x); ra.y = rsqrtf(a.y); ra.z = rsqrtf(a.z); ra.w = rsqrtf(a.w);
        __builtin_nontemporal_store(ra, &out[i]);
    }
}

__global__ void rsqrt_kernel_tail(const float* __restrict__ x, float* __restrict__ out,
                                  long long start, long long n) {
    long long i = start + (long long)blockIdx.x * blockDim.x + threadIdx.x;
    if (i < n) out[i] = rsqrtf(x[i]);
}

extern "C" void kernel_launch(void* const* d_in, const int* in_sizes, int n_in,
                              void* d_out, int out_size, void* d_ws, size_t ws_size,
                              hipStream_t stream) {
    const float* x = (const float*)d_in[0];
    float* out = (float*)d_out;
    long long n = (long long)in_sizes[0];
    long long n4 = n / 4;

    constexpr long long STATIC_GRID = 8192, STATIC_BLOCK = 256, PER_THREAD = 8;
    constexpr long long STATIC_N4 = STATIC_GRID * STATIC_BLOCK * PER_THREAD; // 16M

    if (n4 == STATIC_N4 && n % 4 == 0) {
        rsqrt_kernel_static<<<(int)STATIC_GRID, (int)STATIC_BLOCK, 0, stream>>>(
            (const f32x4*)x, (f32x4*)out);
        return;
    }

    const int block = 256;
    int grid = (int)((n4 + block - 1) / block);
    if (grid > 2048) grid = 2048;
    if (grid > 0) {
        rsqrt_kernel_v4<<<grid, block, 0, stream>>>((const f32x4*)x, (f32x4*)out, n4);
    }
    long long tail_start = n4 * 4;
    long long tail = n - tail_start;
    if (tail > 0) {
        int tgrid = (int)((tail + block - 1) / block);
        rsqrt_kernel_tail<<<tgrid, block, 0, stream>>>(x, out, tail_start, n);
    }
}